// Round 1
// baseline (398.423 us; speedup 1.0000x reference)
//
#include <hip/hip_runtime.h>
#include <hip/hip_fp16.h>
#include <stdint.h>

typedef _Float16 f16;
typedef f16   f16x8 __attribute__((ext_vector_type(8)));
typedef float f32x4 __attribute__((ext_vector_type(4)));

#define NTOK 262144
#define DDIM 256
#define KCB  1024
#define GG   4
#define CC   64

static __device__ __forceinline__ uint32_t umin32(uint32_t a, uint32_t b) { return a < b ? a : b; }

// ---------------- prep: fp32 codebook -> fp16 copy + (0.5 + ||e||^2) table, zero loss acc
__global__ __launch_bounds__(64) void vq_prep(const float* __restrict__ cb,
                                              f16* __restrict__ cb16,
                                              float* __restrict__ esq05,
                                              float* __restrict__ loss_acc) {
    int gk = blockIdx.x;          // 0 .. G*K-1
    int c  = threadIdx.x;         // 0 .. 63
    float v = cb[(size_t)gk * CC + c];
    cb16[(size_t)gk * CC + c] = (f16)v;
    float s = v * v;
    #pragma unroll
    for (int off = 32; off; off >>= 1) s += __shfl_down(s, off, 64);
    if (c == 0) esq05[gk] = 0.5f + s;
    if (gk == 0 && c == 0) *loss_acc = 0.0f;
}

// ---------------- main: fused dots (MFMA fp16) + packed-key argmin + gather + loss partial
__global__ __launch_bounds__(256) void vq_main(const float* __restrict__ z,
                                               const float* __restrict__ cb32,
                                               const f16* __restrict__ cb16,
                                               const float* __restrict__ esq05,
                                               float* __restrict__ out,
                                               float* __restrict__ loss_acc) {
    const int lane = threadIdx.x & 63;
    const int w    = threadIdx.x >> 6;           // wave id (0..3)
    const int g    = blockIdx.y;                 // group
    const int r0   = blockIdx.x * 256 + w * 64;  // this wave's base row
    const int q    = lane >> 4;                  // quarter (k-chunk selector)
    const int t    = lane & 15;                  // within-16 id

    // ---- load A fragments (4 x 16 rows, K=64 split in two 32-halves), fp32 -> fp16
    // A layout for mfma_f32_16x16x32_f16: lane holds row (lane&15), k = (lane>>4)*8 + j
    f16x8 a[4][2];
    float zsq[4];
    #pragma unroll
    for (int f = 0; f < 4; ++f) {
        int row = r0 + f * 16 + t;
        const float* zp = z + (size_t)row * DDIM + g * CC + q * 8;
        float4 v0 = *(const float4*)(zp);
        float4 v1 = *(const float4*)(zp + 4);
        float4 v2 = *(const float4*)(zp + 32);
        float4 v3 = *(const float4*)(zp + 36);
        f16x8 a0 = { (f16)v0.x,(f16)v0.y,(f16)v0.z,(f16)v0.w,
                     (f16)v1.x,(f16)v1.y,(f16)v1.z,(f16)v1.w };
        f16x8 a1 = { (f16)v2.x,(f16)v2.y,(f16)v2.z,(f16)v2.w,
                     (f16)v3.x,(f16)v3.y,(f16)v3.z,(f16)v3.w };
        a[f][0] = a0; a[f][1] = a1;
        float s = v0.x*v0.x + v0.y*v0.y + v0.z*v0.z + v0.w*v0.w
                + v1.x*v1.x + v1.y*v1.y + v1.z*v1.z + v1.w*v1.w
                + v2.x*v2.x + v2.y*v2.y + v2.z*v2.z + v2.w*v2.w
                + v3.x*v3.x + v3.y*v3.y + v3.z*v3.z + v3.w*v3.w;
        // reduce over the 4 quarter-lanes -> full row ||z_g||^2, uniform across quarters
        s += __shfl_xor(s, 16, 64);
        s += __shfl_xor(s, 32, 64);
        zsq[f] = s;   // lane l holds rowsum for row (l&15)
    }

    uint32_t run[4][4];
    #pragma unroll
    for (int f = 0; f < 4; ++f)
        #pragma unroll
        for (int i = 0; i < 4; ++i) run[f][i] = 0xFFFFFFFFu;

    const f16*   cbg = cb16  + (size_t)g * KCB * CC;
    const float* eg  = esq05 + (size_t)g * KCB;

    // ---- K-code loop: 16 codes per iteration
    #pragma unroll 2
    for (int n0 = 0; n0 < KCB; n0 += 16) {
        int code = n0 + t;
        float e = eg[code];                       // 0.5 + ||e||^2  (L2-resident)
        // B layout: lane holds col (lane&15) = code, k = (lane>>4)*8 + j
        const f16x8* bp = (const f16x8*)(cbg + (size_t)code * CC + q * 8);
        f16x8 b0 = bp[0];          // k = 0..31 slice for this lane
        f16x8 b1 = bp[4];          // k = 32..63 slice (+32 halves)
        #pragma unroll
        for (int f = 0; f < 4; ++f) {
            f32x4 acc = {0.f, 0.f, 0.f, 0.f};
            acc = __builtin_amdgcn_mfma_f32_16x16x32_f16(a[f][0], b0, acc, 0, 0, 0);
            acc = __builtin_amdgcn_mfma_f32_16x16x32_f16(a[f][1], b1, acc, 0, 0, 0);
            // C/D layout: col = lane&15 (code), row = (lane>>4)*4 + i   [m89-verified]
            #pragma unroll
            for (int i = 0; i < 4; ++i) {
                float d = fmaf(acc[i], -2.0f, e);               // 0.5 + esq - 2*dot  (> 0)
                uint32_t key = (__float_as_uint(d) & 0xFFFFFC00u) | (uint32_t)code; // v_and_or_b32
                run[f][i] = umin32(run[f][i], key);             // v_min_u32: value then index tiebreak
            }
        }
    }

    // ---- epilogue: cross-lane argmin, gather fp32 code rows, loss partials
    float lsum = 0.0f;
    #pragma unroll
    for (int f = 0; f < 4; ++f) {
        #pragma unroll
        for (int i = 0; i < 4; ++i) {
            uint32_t k = run[f][i];
            k = umin32(k, __shfl_xor(k, 1, 64));
            k = umin32(k, __shfl_xor(k, 2, 64));
            k = umin32(k, __shfl_xor(k, 4, 64));
            k = umin32(k, __shfl_xor(k, 8, 64));   // 16 lanes of each quarter now agree
            int   kw     = (int)(k & 1023u);
            float minval = __uint_as_float(k & 0xFFFFFC00u) - 0.5f;  // esq - 2*dot (truncated)
            int rloc = q * 4 + i;                  // row within this 16-row fragment
            int grow = r0 + f * 16 + rloc;         // global row
            // copy exact fp32 codebook row (256B) with the 16 lanes of this quarter
            const float4* src = (const float4*)(cb32 + ((size_t)(g * KCB + kw)) * CC) + t;
            float4*       dst = (float4*)(out + (size_t)grow * DDIM + g * CC) + t;
            *dst = *src;
            float zs = __shfl(zsq[f], rloc, 64);   // ||z_g||^2 of row rloc (held by lane rloc)
            if (t == 0) lsum += zs + minval;       // Σ_c (zq - zg)^2 for this (row, group)
        }
    }
    #pragma unroll
    for (int off = 32; off; off >>= 1) lsum += __shfl_down(lsum, off, 64);
    if (lane == 0) atomicAdd(loss_acc, lsum);
}

// ---------------- finalize: scale the accumulated squared error into the loss scalar
__global__ void vq_final(const float* __restrict__ loss_acc, float* __restrict__ out_loss) {
    // loss = mean_g(BETA*commit + embed) = 1.5 * total_sq_err / (N*D)
    *out_loss = 1.5f * (*loss_acc) * (1.0f / ((float)NTOK * (float)DDIM));
}

extern "C" void kernel_launch(void* const* d_in, const int* in_sizes, int n_in,
                              void* d_out, int out_size, void* d_ws, size_t ws_size,
                              hipStream_t stream) {
    const float* z  = (const float*)d_in[0];
    const float* cb = (const float*)d_in[1];
    float* out = (float*)d_out;

    char* ws = (char*)d_ws;
    f16*   cb16     = (f16*)ws;                                           // 512 KB
    float* esq05    = (float*)(ws + (size_t)GG * KCB * CC * sizeof(f16)); // 16 KB
    float* loss_acc = (float*)(ws + (size_t)GG * KCB * CC * sizeof(f16)
                                  + (size_t)GG * KCB * sizeof(float));    // 4 B

    vq_prep<<<GG * KCB, 64, 0, stream>>>(cb, cb16, esq05, loss_acc);

    dim3 grid(NTOK / 256, GG);
    vq_main<<<grid, 256, 0, stream>>>(z, cb, cb16, esq05, out, loss_acc);

    vq_final<<<1, 1, 0, stream>>>(loss_acc, out + (size_t)NTOK * DDIM);
}

// Round 2
// 262.022 us; speedup vs baseline: 1.5206x; 1.5206x over previous
//
#include <hip/hip_runtime.h>
#include <hip/hip_fp16.h>
#include <stdint.h>

typedef _Float16 f16;
typedef f16   f16x8 __attribute__((ext_vector_type(8)));
typedef float f32x4 __attribute__((ext_vector_type(4)));

#define NTOK 262144
#define DDIM 256
#define KCB  1024
#define GG   4
#define CC   64
#define FR   8          // 16-row fragments per wave (128 rows/wave)

static __device__ __forceinline__ uint32_t umin32(uint32_t a, uint32_t b) { return a < b ? a : b; }

// ---------------- prep: fp32 codebook -> fp16 copy + (0.5 + ||e||^2) table, zero loss acc
__global__ __launch_bounds__(64) void vq_prep(const float* __restrict__ cb,
                                              f16* __restrict__ cb16,
                                              float* __restrict__ esq05,
                                              float* __restrict__ loss_acc) {
    int gk = blockIdx.x;          // 0 .. G*K-1
    int c  = threadIdx.x;         // 0 .. 63
    float v = cb[(size_t)gk * CC + c];
    cb16[(size_t)gk * CC + c] = (f16)v;
    float s = v * v;
    #pragma unroll
    for (int off = 32; off; off >>= 1) s += __shfl_down(s, off, 64);
    if (c == 0) esq05[gk] = 0.5f + s;
    if (gk == 0 && c == 0) *loss_acc = 0.0f;
}

// ---------------- main: fused dots (MFMA fp16) + packed-key argmin + gather + loss partial
__global__ __launch_bounds__(256) void vq_main(const float* __restrict__ z,
                                               const float* __restrict__ cb32,
                                               const f16* __restrict__ cb16,
                                               const float* __restrict__ esq05,
                                               float* __restrict__ out,
                                               float* __restrict__ loss_acc) {
    const int lane = threadIdx.x & 63;
    const int w    = threadIdx.x >> 6;                 // wave id (0..3)
    const int g    = blockIdx.y;                       // group
    const int r0   = blockIdx.x * (FR * 16 * 4) + w * (FR * 16);  // wave's base row
    const int q    = lane >> 4;                        // quarter (k-chunk selector)
    const int t    = lane & 15;                        // within-16 id

    // ---- load A fragments (FR x 16 rows, K=64 split in two 32-halves), fp32 -> fp16, scaled by -2
    // A layout for mfma_f32_16x16x32_f16: lane holds row (lane&15), k = (lane>>4)*8 + j
    f16x8 a[FR][2];
    float zsq[FR];
    #pragma unroll
    for (int f = 0; f < FR; ++f) {
        int row = r0 + f * 16 + t;
        const float* zp = z + (size_t)row * DDIM + g * CC + q * 8;
        float4 v0 = *(const float4*)(zp);
        float4 v1 = *(const float4*)(zp + 4);
        float4 v2 = *(const float4*)(zp + 32);
        float4 v3 = *(const float4*)(zp + 36);
        f16x8 a0 = { (f16)(-2.f*v0.x),(f16)(-2.f*v0.y),(f16)(-2.f*v0.z),(f16)(-2.f*v0.w),
                     (f16)(-2.f*v1.x),(f16)(-2.f*v1.y),(f16)(-2.f*v1.z),(f16)(-2.f*v1.w) };
        f16x8 a1 = { (f16)(-2.f*v2.x),(f16)(-2.f*v2.y),(f16)(-2.f*v2.z),(f16)(-2.f*v2.w),
                     (f16)(-2.f*v3.x),(f16)(-2.f*v3.y),(f16)(-2.f*v3.z),(f16)(-2.f*v3.w) };
        a[f][0] = a0; a[f][1] = a1;
        float s = v0.x*v0.x + v0.y*v0.y + v0.z*v0.z + v0.w*v0.w
                + v1.x*v1.x + v1.y*v1.y + v1.z*v1.z + v1.w*v1.w
                + v2.x*v2.x + v2.y*v2.y + v2.z*v2.z + v2.w*v2.w
                + v3.x*v3.x + v3.y*v3.y + v3.z*v3.z + v3.w*v3.w;
        s += __shfl_xor(s, 16, 64);
        s += __shfl_xor(s, 32, 64);
        zsq[f] = s;   // lane l holds full ||z_g||^2 for row (l&15)
    }

    uint32_t run[FR][4];
    #pragma unroll
    for (int f = 0; f < FR; ++f)
        #pragma unroll
        for (int i = 0; i < 4; ++i) run[f][i] = 0xFFFFFFFFu;

    const f16*   cbg = cb16  + (size_t)g * KCB * CC;
    const float* eg  = esq05 + (size_t)g * KCB;

    // ---- prologue: load first 16-code tile
    f16x8 b0c, b1c; float ec;
    {
        const f16x8* bp = (const f16x8*)(cbg + (size_t)t * CC + q * 8);
        b0c = bp[0]; b1c = bp[4]; ec = eg[t];
    }

    // ---- K-code loop: 16 codes per iteration, register double-buffered
    for (int n0 = 0; n0 < KCB; n0 += 16) {
        int nn = (n0 + 16) & (KCB - 1);                 // wrap -> harmless redundant load
        const f16x8* nbp = (const f16x8*)(cbg + (size_t)(nn + t) * CC + q * 8);
        f16x8 nb0 = nbp[0];
        f16x8 nb1 = nbp[4];
        float ne  = eg[nn + t];

        uint32_t code = (uint32_t)(n0 + t);
        f32x4 ce = { ec, ec, ec, ec };                  // d = (0.5+esq) + (-2z)·e
        #pragma unroll
        for (int f = 0; f < FR; ++f) {
            f32x4 acc = __builtin_amdgcn_mfma_f32_16x16x32_f16(a[f][0], b0c, ce, 0, 0, 0);
            acc = __builtin_amdgcn_mfma_f32_16x16x32_f16(a[f][1], b1c, acc, 0, 0, 0);
            // C/D layout: col = lane&15 (code), row = (lane>>4)*4 + i
            #pragma unroll
            for (int i = 0; i < 4; ++i) {
                uint32_t key = (__float_as_uint(acc[i]) & 0xFFFFFC00u) | code; // v_and_or_b32
                run[f][i] = umin32(run[f][i], key);                            // v_min_u32
            }
        }
        b0c = nb0; b1c = nb1; ec = ne;
    }

    // ---- epilogue: cross-lane argmin, gather fp32 code rows, loss partials
    float lsum = 0.0f;
    #pragma unroll
    for (int f = 0; f < FR; ++f) {
        #pragma unroll
        for (int i = 0; i < 4; ++i) {
            uint32_t k = run[f][i];
            k = umin32(k, __shfl_xor(k, 1, 64));
            k = umin32(k, __shfl_xor(k, 2, 64));
            k = umin32(k, __shfl_xor(k, 4, 64));
            k = umin32(k, __shfl_xor(k, 8, 64));   // 16 lanes of each quarter now agree
            int   kw     = (int)(k & 1023u);
            float minval = __uint_as_float(k & 0xFFFFFC00u) - 0.5f;  // esq - 2*dot (truncated)
            int rloc = q * 4 + i;                  // row within this 16-row fragment
            int grow = r0 + f * 16 + rloc;         // global row
            // copy exact fp32 codebook row (256B) with the 16 lanes of this quarter
            const float4* src = (const float4*)(cb32 + ((size_t)(g * KCB + kw)) * CC) + t;
            float4*       dst = (float4*)(out + (size_t)grow * DDIM + g * CC) + t;
            *dst = *src;
            float zs = __shfl(zsq[f], rloc, 64);   // ||z_g||^2 of row rloc (held by lane rloc)
            if (t == 0) lsum += zs + minval;       // Σ_c (zq - zg)^2 for this (row, group)
        }
    }
    #pragma unroll
    for (int off = 32; off; off >>= 1) lsum += __shfl_down(lsum, off, 64);
    if (lane == 0) atomicAdd(loss_acc, lsum);
}

// ---------------- finalize: scale the accumulated squared error into the loss scalar
__global__ void vq_final(const float* __restrict__ loss_acc, float* __restrict__ out_loss) {
    // loss = mean_g(BETA*commit + embed) = 1.5 * total_sq_err / (N*D)
    *out_loss = 1.5f * (*loss_acc) * (1.0f / ((float)NTOK * (float)DDIM));
}

extern "C" void kernel_launch(void* const* d_in, const int* in_sizes, int n_in,
                              void* d_out, int out_size, void* d_ws, size_t ws_size,
                              hipStream_t stream) {
    const float* z  = (const float*)d_in[0];
    const float* cb = (const float*)d_in[1];
    float* out = (float*)d_out;

    char* ws = (char*)d_ws;
    f16*   cb16     = (f16*)ws;                                           // 512 KB
    float* esq05    = (float*)(ws + (size_t)GG * KCB * CC * sizeof(f16)); // 16 KB
    float* loss_acc = (float*)(ws + (size_t)GG * KCB * CC * sizeof(f16)
                                  + (size_t)GG * KCB * sizeof(float));    // 4 B

    vq_prep<<<GG * KCB, 64, 0, stream>>>(cb, cb16, esq05, loss_acc);

    dim3 grid(NTOK / (FR * 16 * 4), GG);   // 512 x 4
    vq_main<<<grid, 256, 0, stream>>>(z, cb, cb16, esq05, out, loss_acc);

    vq_final<<<1, 1, 0, stream>>>(loss_acc, out + (size_t)NTOK * DDIM);
}